// Round 11
// baseline (89.466 us; speedup 1.0000x reference)
//
#include <hip/hip_runtime.h>
#include <math.h>

#define EPS 1e-12f
#define EDIR 0.57735027f
#define M2E  -1.15470054f   // -2*EDIR

#define NB 8      // batches
#define NS 256    // skel points
#define NP 4096   // shape points
#define NM 256    // l3 points

#define NSLOT 64
#define SLOTW 32
#define ACC_F (NSLOT * SLOTW)

// term slots
#define T_CD1   0
#define T_CD2   1
#define T_P2SN  2
#define T_P2SJ  3
#define T_NORM  5
#define T_ND    6
#define T_NS    7
#define T_SKN_SUM 8    // +b
#define T_SKN_SQ  16   // +b

// k_sp: skelrow blocks then prep blocks
#define NBLK_SKEL 512
#define NBLK_PREP 128
#define NBLK_SP   (NBLK_SKEL + NBLK_PREP)

// k_rest role block ranges
// cd1: 16384 rows, 4 rows/wave, 2 sweep-halves -> 8192 waves -> 2048 blocks
#define NBLK_CD1  2048
#define NBLK_CD2  1024         // 32768 shape-rows / 8rows / 4 waves (analytic 4-iter)
#define NBLK_SKN  240
#define B0_CD2  (NBLK_CD1)
#define B0_SKN  (B0_CD2 + NBLK_CD2)
#define NBLK_REST (B0_SKN + NBLK_SKN)

__device__ __forceinline__ unsigned umin2(unsigned a, unsigned b){ return a<b?a:b; }
__device__ __forceinline__ unsigned umax2(unsigned a, unsigned b){ return a>b?a:b; }

// order-preserving float<->uint for atomicMin
__device__ __forceinline__ unsigned fenc(float f){
  unsigned u = __float_as_uint(f);
  return (u & 0x80000000u) ? ~u : (u | 0x80000000u);
}
__device__ __forceinline__ float fdec(unsigned u){
  return (u & 0x80000000u) ? __uint_as_float(u ^ 0x80000000u) : __uint_as_float(~u);
}

__device__ __forceinline__ float wave_min(float v){
#pragma unroll
  for (int o = 32; o; o >>= 1) v = fminf(v, __shfl_xor(v, o));
  return v;
}
__device__ __forceinline__ float wave_max(float v){
#pragma unroll
  for (int o = 32; o; o >>= 1) v = fmaxf(v, __shfl_xor(v, o));
  return v;
}
__device__ __forceinline__ float wave_sum(float v){
#pragma unroll
  for (int o = 32; o; o >>= 1) v += __shfl_xor(v, o);
  return v;
}
__device__ __forceinline__ unsigned wave_min_u(unsigned v){
#pragma unroll
  for (int o = 32; o; o >>= 1){ unsigned w = __shfl_xor(v, o); v = (w < v) ? w : v; }
  return v;
}
__device__ __forceinline__ unsigned wave_max_u(unsigned v){
#pragma unroll
  for (int o = 32; o; o >>= 1){ unsigned w = __shfl_xor(v, o); v = (w > v) ? w : v; }
  return v;
}
__device__ __forceinline__ unsigned long long wave_min_u64(unsigned long long v){
#pragma unroll
  for (int o = 32; o; o >>= 1){
    unsigned long long w = __shfl_xor(v, o);
    v = (w < v) ? w : v;
  }
  return v;
}

// ws layout (floats). Packed points carry |p|^2 in .w
#define OFF_SMP (ACC_F)
#define OFF_SKR (OFF_SMP + NB*2048*4)
#define OFF_SXY (OFF_SKR + NB*NS*4)
#define OFF_L3P (OFF_SXY + NB*NP*4)
#define OFF_NR4 (OFF_L3P + NB*NM*4)
#define OFF_C1M (OFF_NR4 + NB*NS*4)   // NB*2048 u32 row-min (encoded)

// ---- dispatch 1: skelrow (raw inputs only) + prep roles ----
__global__ __launch_bounds__(256) void k_sp(const float* __restrict__ skel,
                                            const float* __restrict__ rad,
                                            const float* __restrict__ nori,
                                            const float* __restrict__ l3,
                                            const float* __restrict__ shape,
                                            float* __restrict__ ws){
  int bid = blockIdx.x;
  int tid = threadIdx.x;

  if (bid >= NBLK_SKEL){
    // ---- prep role: pack points (|p|^2 in .w). acc zeroing done by memset. ----
    int i = (bid - NBLK_SKEL) * 256 + tid;   // 0..32767
    float4* smp = (float4*)(ws + OFF_SMP);
    float4* skr = (float4*)(ws + OFF_SKR);
    float4* sxy = (float4*)(ws + OFF_SXY);
    float4* l3p = (float4*)(ws + OFF_L3P);
    float4* nr4 = (float4*)(ws + OFF_NR4);
    {
      const float* q = shape + (size_t)i * 6;
      float x = q[0], y = q[1], z = q[2];
      sxy[i] = make_float4(x, y, z, fmaf(x, x, fmaf(y, y, z * z)));
    }
    if (i < NB * 2048){
      int b = i >> 11, m = i & 2047;
      int si = m >> 3, k = m & 7;
      const float* sp = skel + (size_t)(b * NS + si) * 3;
      float r = rad[b * NS + si];
      float x = sp[0] + r * ((k & 4) ? -EDIR : EDIR);
      float y = sp[1] + r * ((k & 2) ? -EDIR : EDIR);
      float z = sp[2] + r * ((k & 1) ? -EDIR : EDIR);
      smp[i] = make_float4(x, y, z, fmaf(x, x, fmaf(y, y, z * z)));
    }
    if (i < NB * NS){
      const float* sp = skel + (size_t)i * 3;
      skr[i] = make_float4(sp[0], sp[1], sp[2], rad[i]);
      const float* nn = nori + (size_t)i * 3;
      nr4[i] = make_float4(nn[0], nn[1], nn[2], 0.0f);
      const float* lp = l3 + (size_t)i * 3;
      float x = lp[0], y = lp[1], z = lp[2];
      l3p[i] = make_float4(x, y, z, fmaf(x, x, fmaf(y, y, z * z)));
    }
    return;
  }

  // ---- skelrow role: per (b, skel j): p2s_j + top30 normal + top3 ns + nd ----
  int wid  = tid >> 6;
  int lane = tid & 63;
  int row  = bid * 4 + wid;          // 0..2047
  int b = row >> 8;
  const float* sjp = skel + (size_t)row * 3;
  float cx = sjp[0], cy = sjp[1], cz = sjp[2];
  float rj = rad[row];
  float r2j = rj * rj;
  const float* njp = nori + (size_t)row * 3;
  float nx = njp[0], ny = njp[1], nz = njp[2];
  const float* shb = shape + (size_t)b * NP * 6;

  // two independent per-lane top-6 sort chains; keys = (dsq bits & ~0xFFF) | idx
  unsigned a0=~0u,a1=~0u,a2=~0u,a3=~0u,a4=~0u,a5=~0u;
  unsigned b0=~0u,b1=~0u,b2=~0u,b3=~0u,b4=~0u,b5=~0u;
  float dmoA = 3.4e38f, dmiA = -3.4e38f, dmoB = 3.4e38f, dmiB = -3.4e38f;

#pragma unroll 2
  for (int s = 0; s < 32; ++s){
    int nA = s * 128 + lane;
    int nB = nA + 64;
    float2 xyA = *(const float2*)(shb + (size_t)nA * 6);
    float  zA  = shb[(size_t)nA * 6 + 2];
    float2 xyB = *(const float2*)(shb + (size_t)nB * 6);
    float  zB  = shb[(size_t)nB * 6 + 2];
    float dxA = xyA.x - cx, dyA = xyA.y - cy, dzA = zA - cz;
    float dxB = xyB.x - cx, dyB = xyB.y - cy, dzB = zB - cz;
    float dA = fmaf(dxA, dxA, fmaf(dyA, dyA, dzA * dzA));
    float dB = fmaf(dxB, dxB, fmaf(dyB, dyB, dzB * dzB));
    bool inA = dA < r2j;
    bool inB = dB < r2j;
    dmoA = fminf(dmoA, inA ? 3.4e38f : dA);
    dmiA = fmaxf(dmiA, inA ? dA : -3.4e38f);
    dmoB = fminf(dmoB, inB ? 3.4e38f : dB);
    dmiB = fmaxf(dmiB, inB ? dB : -3.4e38f);
    unsigned uA = (__float_as_uint(dA) & 0xFFFFF000u) | (unsigned)nA;
    unsigned uB = (__float_as_uint(dB) & 0xFFFFF000u) | (unsigned)nB;
    a5 = umin2(a5, uA);
    { unsigned p = umin2(a4, a5), q = umax2(a4, a5); a4 = p; a5 = q; }
    { unsigned p = umin2(a3, a4), q = umax2(a3, a4); a3 = p; a4 = q; }
    { unsigned p = umin2(a2, a3), q = umax2(a2, a3); a2 = p; a3 = q; }
    { unsigned p = umin2(a1, a2), q = umax2(a1, a2); a1 = p; a2 = q; }
    { unsigned p = umin2(a0, a1), q = umax2(a0, a1); a0 = p; a1 = q; }
    b5 = umin2(b5, uB);
    { unsigned p = umin2(b4, b5), q = umax2(b4, b5); b4 = p; b5 = q; }
    { unsigned p = umin2(b3, b4), q = umax2(b3, b4); b3 = p; b4 = q; }
    { unsigned p = umin2(b2, b3), q = umax2(b2, b3); b2 = p; b3 = q; }
    { unsigned p = umin2(b1, b2), q = umax2(b1, b2); b1 = p; b2 = q; }
    { unsigned p = umin2(b0, b1), q = umax2(b0, b1); b0 = p; b1 = q; }
  }
  float dmin_out = wave_min(fminf(dmoA, dmoB));
  float dmax_in  = wave_max(fmaxf(dmiA, dmiB));
  float pmin = sqrtf(fmaxf(dmin_out, EPS)) - rj;
  float pin  = (dmax_in >= 0.0f) ? (rj - sqrtf(fmaxf(dmax_in, EPS))) : 3.4e38f;
  pmin = fminf(pmin, pin);

  // rank-30 threshold via ballot-count binary search (keys distinct -> exact)
  unsigned lmin = umin2(a0, b0);
  unsigned lo = wave_min_u(lmin), hi = wave_max_u(lmin);
  while (lo < hi){
    unsigned mid = lo + ((hi - lo) >> 1);
    int c = __popcll(__ballot(a0 <= mid)) + __popcll(__ballot(a1 <= mid)) +
            __popcll(__ballot(a2 <= mid)) + __popcll(__ballot(a3 <= mid)) +
            __popcll(__ballot(a4 <= mid)) + __popcll(__ballot(a5 <= mid)) +
            __popcll(__ballot(b0 <= mid)) + __popcll(__ballot(b1 <= mid)) +
            __popcll(__ballot(b2 <= mid)) + __popcll(__ballot(b3 <= mid)) +
            __popcll(__ballot(b4 <= mid)) + __popcll(__ballot(b5 <= mid));
    if (c >= 30) hi = mid; else lo = mid + 1;
  }
  unsigned tau = hi;

  // gather |dot(nori_j, normal_n)| for the exactly-30 winners
  float dsum = 0.0f;
  {
    unsigned mm[12] = {a0,a1,a2,a3,a4,a5,b0,b1,b2,b3,b4,b5};
#pragma unroll
    for (int r = 0; r < 12; ++r){
      if (mm[r] <= tau){
        int idx = (int)(mm[r] & 0xFFFu);
        const float* qq = shb + (size_t)idx * 6;
        dsum += fabsf(fmaf(nx, qq[3], fmaf(ny, qq[4], nz * qq[5])));
      }
    }
  }
  dsum = wave_sum(dsum);

  // ns: 3 nearest skel points (incl. self)
  const float* skb = skel + (size_t)b * NS * 3;
  const float* nb  = nori + (size_t)b * NS * 3;
  unsigned u0=~0u,u1=~0u,u2=~0u; int i0=0,i1=0,i2=0;
#pragma unroll
  for (int it = 0; it < 4; ++it){
    int n2i = it * 64 + lane;
    float dx = skb[n2i*3+0] - cx, dy = skb[n2i*3+1] - cy, dz = skb[n2i*3+2] - cz;
    unsigned u = __float_as_uint(fmaf(dx,dx,fmaf(dy,dy,dz*dz)));
    if (u < u2){ u2 = u; i2 = n2i; }
    if (u2 < u1){ unsigned t=u1;u1=u2;u2=t; int ti=i1;i1=i2;i2=ti; }
    if (u1 < u0){ unsigned t=u0;u0=u1;u1=t; int ti=i0;i0=i1;i1=ti; }
  }
  int cc = 0;
  float nssum = 0.0f;
#pragma unroll
  for (int r = 0; r < 3; ++r){
    unsigned hu = (cc==0)?u0:((cc==1)?u1:u2);
    int      hix= (cc==0)?i0:((cc==1)?i1:i2);
    unsigned long long pack = (((unsigned long long)hu) << 32) | (unsigned)hix;
    unsigned long long best = wave_min_u64(pack);
    if (pack == best) cc++;
    int idx = (int)(best & 0xffffffffull);
    if (lane == 0){
      float axn = nb[idx*3+0]-nx, ayn = nb[idx*3+1]-ny, azn = nb[idx*3+2]-nz;
      nssum += sqrtf(fmaf(axn,axn,fmaf(ayn,ayn,azn*azn)) + EPS);
    }
  }

  if (lane == 0){
    float nrm = sqrtf(nx*nx + ny*ny + nz*nz + EPS);
    float ndv = expf(0.3f - nrm) + ((nrm < 0.25f) ? 5.0f : 0.0f);
    float* slot = ws + (size_t)(row & (NSLOT - 1)) * SLOTW;
    atomicAdd(slot + T_P2SJ, pmin);
    atomicAdd(slot + T_NORM, dsum * (1.0f / 30.0f));
    atomicAdd(slot + T_NS,   nssum);
    atomicAdd(slot + T_ND,   ndv);
  }
}

// ---- dispatch 2: cd1 (split, atomicMin) + cd2/p2sn (analytic) + skn. NO fences. ----
__global__ __launch_bounds__(256) void k_rest(float* __restrict__ ws){
  __shared__ float4 lsh[NM];
  __shared__ float r1[4], r2[4];
  const float4* smp = (const float4*)(ws + OFF_SMP);
  const float4* skr = (const float4*)(ws + OFF_SKR);
  const float4* sxy = (const float4*)(ws + OFF_SXY);
  const float4* l3p = (const float4*)(ws + OFF_L3P);
  const float4* nr4 = (const float4*)(ws + OFF_NR4);
  unsigned* c1m = (unsigned*)(ws + OFF_C1M);
  int bid  = blockIdx.x;
  int tid  = threadIdx.x;
  int wid  = tid >> 6;
  int lane = tid & 63;

  if (bid < NBLK_CD1){
    // ---- cd1: 4 sample-rows per wave, half the 4096-pt sweep; atomicMin combine ----
    int wv   = bid * 4 + wid;              // 0..8191
    int rg   = wv >> 1;                    // 0..4095 (row group of 4)
    int half = wv & 1;
    int row0 = rg * 4;                     // 0..16380 (same batch within group)
    int b    = row0 >> 11;
    float ax[4], ay[4], az[4];
#pragma unroll
    for (int i = 0; i < 4; ++i){
      float4 c = smp[row0 + i];
      ax[i] = -2.0f * c.x; ay[i] = -2.0f * c.y; az[i] = -2.0f * c.z;
    }
    const float4* sh = sxy + (size_t)b * NP + half * 2048;
    float mn[4];
#pragma unroll
    for (int i = 0; i < 4; ++i) mn[i] = 3.4e38f;
#pragma unroll 8
    for (int s = 0; s < 32; ++s){
      float4 p = sh[s * 64 + lane];
#pragma unroll
      for (int i = 0; i < 4; ++i){
        float t = fmaf(p.x, ax[i], fmaf(p.y, ay[i], fmaf(p.z, az[i], p.w)));
        mn[i] = fminf(mn[i], t);
      }
    }
#pragma unroll
    for (int i = 0; i < 4; ++i){
      float m = wave_min(mn[i]);
      if (lane == 0) atomicMin(c1m + row0 + i, fenc(m));
    }

  } else if (bid < B0_SKN){
    // ---- cd2 + p2s_n: 8 shape-rows per wave; 256-skel sweep, analytic 8-corner min ----
    int wv   = (bid - B0_CD2) * 4 + wid;   // 0..4095
    int row0 = wv * 8;                     // 0..32767
    int b    = row0 >> 12;
    float cx[8], cy[8], cz[8];
#pragma unroll
    for (int i = 0; i < 8; ++i){
      float4 c = sxy[row0 + i];
      cx[i] = c.x; cy[i] = c.y; cz[i] = c.z;
    }
    const float4* kb = skr + (size_t)b * NS;
    float mn[8], pm[8];
#pragma unroll
    for (int i = 0; i < 8; ++i){ mn[i] = 3.4e38f; pm[i] = 3.4e38f; }
#pragma unroll
    for (int it = 0; it < 4; ++it){
      float4 kr = kb[it * 64 + lane];
      float rr = kr.w;
      float r2 = rr * rr;
      float c1 = M2E * rr;                 // -2*e*r
#pragma unroll
      for (int i = 0; i < 8; ++i){
        float dx = cx[i] - kr.x, dy = cy[i] - kr.y, dz = cz[i] - kr.z;
        float q  = fmaf(dx, dx, fmaf(dy, dy, dz * dz));
        float s  = (fabsf(dx) + fabsf(dy)) + fabsf(dz);
        mn[i] = fminf(mn[i], fmaf(c1, s, q + r2));   // min over 8 corners, analytic
        float d = sqrtf(fmaxf(q, EPS));
        pm[i] = fminf(pm[i], fabsf(d - rr));
      }
    }
    float cdv = 0.0f, pv = 0.0f;
#pragma unroll
    for (int i = 0; i < 8; ++i){
      float m = wave_min(mn[i]);
      cdv += sqrtf(fmaxf(m, EPS));
      pv  += wave_min(pm[i]);
    }
    if (lane == 0){
      float* slot = ws + (size_t)(bid & (NSLOT - 1)) * SLOTW;
      atomicAdd(slot + T_CD2, cdv);
      atomicAdd(slot + T_P2SN, pv);
    }

  } else {
    // ---- skn: thread per combine point ----
    int q  = bid - B0_SKN;           // 0..239
    int b  = q / 30;
    int t  = (q % 30) * 256 + tid;   // 0..7679
    lsh[tid] = l3p[(size_t)b * NM + tid];
    __syncthreads();
    int s = t >> 8;
    int j = t & 255;
    float ksf = (float)s * (1.0f / 30.0f);
    float4 sj = skr[(size_t)b * NS + j];
    float4 nj = nr4[(size_t)b * NS + j];
    float px = fmaf(nj.x, ksf, sj.x);
    float py = fmaf(nj.y, ksf, sj.y);
    float pz = fmaf(nj.z, ksf, sj.z);
    float ax = -2.0f * px, ay = -2.0f * py, az = -2.0f * pz;
    float pw = fmaf(px, px, fmaf(py, py, pz * pz));
    float mn = 3.4e38f;
#pragma unroll 8
    for (int qq = 0; qq < NM; ++qq){
      float4 L = lsh[qq];
      float t2 = fmaf(L.x, ax, fmaf(L.y, ay, fmaf(L.z, az, L.w)));
      mn = fminf(mn, t2);
    }
    float d = sqrtf(fmaxf(mn + pw, EPS));
    float s1 = wave_sum(d);
    float s2 = wave_sum(d * d);
    if (lane == 0){ r1[wid] = s1; r2[wid] = s2; }
    __syncthreads();
    if (tid == 0){
      float a1 = r1[0]+r1[1]+r1[2]+r1[3];
      float a2 = r2[0]+r2[1]+r2[2]+r2[3];
      float* slot = ws + (size_t)(bid & (NSLOT - 1)) * SLOTW;
      atomicAdd(slot + T_SKN_SUM + b, a1);
      atomicAdd(slot + T_SKN_SQ  + b, a2);
    }
  }
}

// ---- finalize (separate tiny dispatch; fence-free) ----
__global__ __launch_bounds__(256) void k_final(const float* __restrict__ rad,
                                               const float* __restrict__ ws,
                                               const int* w0, const int* w1, const int* w2,
                                               const int* w4, const int* w5, const int* w6,
                                               float* __restrict__ out){
  __shared__ float A[SLOTW];
  __shared__ float rs[256];
  __shared__ float cs[256];
  int tid = threadIdx.x;
  if (tid < SLOTW){
    float v = 0.0f;
    for (int s = 0; s < NSLOT; ++s) v += ws[(size_t)s * SLOTW + tid];
    A[tid] = v;
  }
  float r = 0.0f;
  for (int q = tid; q < NB * NS; q += 256) r += rad[q];
  rs[tid] = r;
  // cd1: decode per-row min, add |c|^2, clamp, sqrt, sum
  const unsigned* c1m = (const unsigned*)(ws + OFF_C1M);
  const float4*   smp = (const float4*)(ws + OFF_SMP);
  float c1 = 0.0f;
  for (int q = tid; q < NB * 2048; q += 256){
    unsigned u = c1m[q];
    float m = (u & 0x80000000u) ? __uint_as_float(u ^ 0x80000000u) : __uint_as_float(~u);
    c1 += sqrtf(fmaxf(m + smp[q].w, EPS));
  }
  cs[tid] = c1;
  __syncthreads();
  if (tid == 0){
    float srad = 0.0f, c1t = 0.0f;
    for (int q = 0; q < 256; ++q){ srad += rs[q]; c1t += cs[q]; }
    float ls = c1t * (1.0f/2048.0f) + A[T_CD2] * (1.0f/4096.0f);
    float lp = A[T_P2SN] * (1.0f/4096.0f) + A[T_P2SJ] * (1.0f/256.0f);
    float lr = -srad * (1.0f/256.0f);
    float ln = A[T_NORM] * (1.0f/8.0f);
    float smind = 0.0f, vsum = 0.0f;
    for (int bb = 0; bb < NB; ++bb){
      float s1 = A[T_SKN_SUM + bb], s2 = A[T_SKN_SQ + bb];
      smind += s1;
      vsum  += (s2 - s1 * s1 * (1.0f/7680.0f)) * (1.0f/7679.0f);
    }
    float lskn = 50.0f * smind * (1.0f/(8.0f*7680.0f)) + 500.0f * vsum * (1.0f/8.0f);
    float lnd = A[T_ND] * (1.0f/2048.0f);
    float lns = A[T_NS] * (1.0f/6144.0f);
    float o = (float)w0[0]*ls + (float)w1[0]*lp + (float)w2[0]*lr +
              (float)w4[0]*ln + (float)w5[0]*lskn + (float)w6[0]*lnd + 0.1f*lns;
    out[0] = o;
  }
}

extern "C" void kernel_launch(void* const* d_in, const int* in_sizes, int n_in,
                              void* d_out, int out_size, void* d_ws, size_t ws_size,
                              hipStream_t stream) {
  const float* skel  = (const float*)d_in[0];
  const float* rad   = (const float*)d_in[1];
  const float* nori  = (const float*)d_in[3];
  const float* l3    = (const float*)d_in[5];
  const float* shape = (const float*)d_in[7];
  const int* w0 = (const int*)d_in[9];
  const int* w1 = (const int*)d_in[10];
  const int* w2 = (const int*)d_in[11];
  const int* w4 = (const int*)d_in[13];
  const int* w5 = (const int*)d_in[14];
  const int* w6 = (const int*)d_in[15];
  float* ws  = (float*)d_ws;
  float* out = (float*)d_out;

  hipMemsetAsync(ws, 0, ACC_F * sizeof(float), stream);
  hipMemsetAsync(ws + OFF_C1M, 0xFF, NB * 2048 * sizeof(unsigned), stream);
  k_sp<<<dim3(NBLK_SP), dim3(256), 0, stream>>>(skel, rad, nori, l3, shape, ws);
  k_rest<<<dim3(NBLK_REST), dim3(256), 0, stream>>>(ws);
  k_final<<<dim3(1), dim3(256), 0, stream>>>(rad, ws, w0, w1, w2, w4, w5, w6, out);
}

// Round 12
// 85.779 us; speedup vs baseline: 1.0430x; 1.0430x over previous
//
#include <hip/hip_runtime.h>
#include <math.h>

#define EPS 1e-12f
#define EDIR 0.57735027f
#define M2E  -1.15470054f   // -2*EDIR

#define NB 8      // batches
#define NS 256    // skel points
#define NP 4096   // shape points
#define NM 256    // l3 points

#define NSLOT 64
#define SLOTW 32
#define ACC_F (NSLOT * SLOTW)

// term slots (cd2/skn only now)
#define T_CD2   1
#define T_P2SN  2
#define T_SKN_SUM 8    // +b
#define T_SKN_SQ  16   // +b

// k_sp: skelrow blocks then prep blocks
#define NBLK_SKEL 512
#define NBLK_PREP 128
#define NBLK_SP   (NBLK_SKEL + NBLK_PREP)

// k_cd1: 2048 skels / 2 per wave * 4 sweep-quarters = 4096 waves = 1024 blocks
#define NBLK_CD1  1024
// k_rest2: cd2 (1024) + skn (240)
#define NBLK_CD2  1024
#define NBLK_SKN  240
#define NBLK_REST2 (NBLK_CD2 + NBLK_SKN)

__device__ __forceinline__ unsigned umin2(unsigned a, unsigned b){ return a<b?a:b; }
__device__ __forceinline__ unsigned umax2(unsigned a, unsigned b){ return a>b?a:b; }

// order-preserving float<->uint for atomicMin
__device__ __forceinline__ unsigned fenc(float f){
  unsigned u = __float_as_uint(f);
  return (u & 0x80000000u) ? ~u : (u | 0x80000000u);
}

__device__ __forceinline__ float wave_min(float v){
#pragma unroll
  for (int o = 32; o; o >>= 1) v = fminf(v, __shfl_xor(v, o));
  return v;
}
__device__ __forceinline__ float wave_max(float v){
#pragma unroll
  for (int o = 32; o; o >>= 1) v = fmaxf(v, __shfl_xor(v, o));
  return v;
}
__device__ __forceinline__ float wave_sum(float v){
#pragma unroll
  for (int o = 32; o; o >>= 1) v += __shfl_xor(v, o);
  return v;
}
__device__ __forceinline__ unsigned wave_min_u(unsigned v){
#pragma unroll
  for (int o = 32; o; o >>= 1){ unsigned w = __shfl_xor(v, o); v = (w < v) ? w : v; }
  return v;
}
__device__ __forceinline__ unsigned wave_max_u(unsigned v){
#pragma unroll
  for (int o = 32; o; o >>= 1){ unsigned w = __shfl_xor(v, o); v = (w > v) ? w : v; }
  return v;
}
__device__ __forceinline__ unsigned long long wave_min_u64(unsigned long long v){
#pragma unroll
  for (int o = 32; o; o >>= 1){
    unsigned long long w = __shfl_xor(v, o);
    v = (w < v) ? w : v;
  }
  return v;
}

// ws layout (floats). sxy/l3p carry |p|^2 in .w
#define OFF_SKR (ACC_F)
#define OFF_SXY (OFF_SKR + NB*NS*4)
#define OFF_L3P (OFF_SXY + NB*NP*4)
#define OFF_NR4 (OFF_L3P + NB*NM*4)
#define OFF_C1M (OFF_NR4 + NB*NS*4)     // 16384 u32 row-min (encoded dist^2)
#define OFF_SKO (OFF_C1M + NB*2048)     // 2048 rows x 4: pmin, norm, ns, nd

// ---- dispatch 1: skelrow (raw inputs, indexed outputs) + prep ----
__global__ __launch_bounds__(256) void k_sp(const float* __restrict__ skel,
                                            const float* __restrict__ rad,
                                            const float* __restrict__ nori,
                                            const float* __restrict__ l3,
                                            const float* __restrict__ shape,
                                            float* __restrict__ ws){
  int bid = blockIdx.x;
  int tid = threadIdx.x;

  if (bid >= NBLK_SKEL){
    // ---- prep: pack points, zero acc slots, init C1M ----
    int i = (bid - NBLK_SKEL) * 256 + tid;   // 0..32767
    float4* skr = (float4*)(ws + OFF_SKR);
    float4* sxy = (float4*)(ws + OFF_SXY);
    float4* l3p = (float4*)(ws + OFF_L3P);
    float4* nr4 = (float4*)(ws + OFF_NR4);
    unsigned* c1m = (unsigned*)(ws + OFF_C1M);
    {
      const float* q = shape + (size_t)i * 6;
      float x = q[0], y = q[1], z = q[2];
      sxy[i] = make_float4(x, y, z, fmaf(x, x, fmaf(y, y, z * z)));
    }
    if (i < ACC_F) ws[i] = 0.0f;
    if (i < NB * 2048) c1m[i] = ~0u;
    if (i < NB * NS){
      const float* sp = skel + (size_t)i * 3;
      skr[i] = make_float4(sp[0], sp[1], sp[2], rad[i]);
      const float* nn = nori + (size_t)i * 3;
      nr4[i] = make_float4(nn[0], nn[1], nn[2], 0.0f);
      const float* lp = l3 + (size_t)i * 3;
      float x = lp[0], y = lp[1], z = lp[2];
      l3p[i] = make_float4(x, y, z, fmaf(x, x, fmaf(y, y, z * z)));
    }
    return;
  }

  // ---- skelrow role: per (b, skel j): p2s_j + top30 normal + top3 ns + nd ----
  int wid  = tid >> 6;
  int lane = tid & 63;
  int row  = bid * 4 + wid;          // 0..2047
  int b = row >> 8;
  const float* sjp = skel + (size_t)row * 3;
  float cx = sjp[0], cy = sjp[1], cz = sjp[2];
  float rj = rad[row];
  float r2j = rj * rj;
  const float* njp = nori + (size_t)row * 3;
  float nx = njp[0], ny = njp[1], nz = njp[2];
  const float* shb = shape + (size_t)b * NP * 6;

  unsigned a0=~0u,a1=~0u,a2=~0u,a3=~0u,a4=~0u,a5=~0u;
  unsigned b0=~0u,b1=~0u,b2=~0u,b3=~0u,b4=~0u,b5=~0u;
  float dmoA = 3.4e38f, dmiA = -3.4e38f, dmoB = 3.4e38f, dmiB = -3.4e38f;

#pragma unroll 2
  for (int s = 0; s < 32; ++s){
    int nA = s * 128 + lane;
    int nB = nA + 64;
    float2 xyA = *(const float2*)(shb + (size_t)nA * 6);
    float  zA  = shb[(size_t)nA * 6 + 2];
    float2 xyB = *(const float2*)(shb + (size_t)nB * 6);
    float  zB  = shb[(size_t)nB * 6 + 2];
    float dxA = xyA.x - cx, dyA = xyA.y - cy, dzA = zA - cz;
    float dxB = xyB.x - cx, dyB = xyB.y - cy, dzB = zB - cz;
    float dA = fmaf(dxA, dxA, fmaf(dyA, dyA, dzA * dzA));
    float dB = fmaf(dxB, dxB, fmaf(dyB, dyB, dzB * dzB));
    bool inA = dA < r2j;
    bool inB = dB < r2j;
    dmoA = fminf(dmoA, inA ? 3.4e38f : dA);
    dmiA = fmaxf(dmiA, inA ? dA : -3.4e38f);
    dmoB = fminf(dmoB, inB ? 3.4e38f : dB);
    dmiB = fmaxf(dmiB, inB ? dB : -3.4e38f);
    unsigned uA = (__float_as_uint(dA) & 0xFFFFF000u) | (unsigned)nA;
    unsigned uB = (__float_as_uint(dB) & 0xFFFFF000u) | (unsigned)nB;
    a5 = umin2(a5, uA);
    { unsigned p = umin2(a4, a5), q = umax2(a4, a5); a4 = p; a5 = q; }
    { unsigned p = umin2(a3, a4), q = umax2(a3, a4); a3 = p; a4 = q; }
    { unsigned p = umin2(a2, a3), q = umax2(a2, a3); a2 = p; a3 = q; }
    { unsigned p = umin2(a1, a2), q = umax2(a1, a2); a1 = p; a2 = q; }
    { unsigned p = umin2(a0, a1), q = umax2(a0, a1); a0 = p; a1 = q; }
    b5 = umin2(b5, uB);
    { unsigned p = umin2(b4, b5), q = umax2(b4, b5); b4 = p; b5 = q; }
    { unsigned p = umin2(b3, b4), q = umax2(b3, b4); b3 = p; b4 = q; }
    { unsigned p = umin2(b2, b3), q = umax2(b2, b3); b2 = p; b3 = q; }
    { unsigned p = umin2(b1, b2), q = umax2(b1, b2); b1 = p; b2 = q; }
    { unsigned p = umin2(b0, b1), q = umax2(b0, b1); b0 = p; b1 = q; }
  }
  float dmin_out = wave_min(fminf(dmoA, dmoB));
  float dmax_in  = wave_max(fmaxf(dmiA, dmiB));
  float pmin = sqrtf(fmaxf(dmin_out, EPS)) - rj;
  float pin  = (dmax_in >= 0.0f) ? (rj - sqrtf(fmaxf(dmax_in, EPS))) : 3.4e38f;
  pmin = fminf(pmin, pin);

  unsigned lmin = umin2(a0, b0);
  unsigned lo = wave_min_u(lmin), hi = wave_max_u(lmin);
  while (lo < hi){
    unsigned mid = lo + ((hi - lo) >> 1);
    int c = __popcll(__ballot(a0 <= mid)) + __popcll(__ballot(a1 <= mid)) +
            __popcll(__ballot(a2 <= mid)) + __popcll(__ballot(a3 <= mid)) +
            __popcll(__ballot(a4 <= mid)) + __popcll(__ballot(a5 <= mid)) +
            __popcll(__ballot(b0 <= mid)) + __popcll(__ballot(b1 <= mid)) +
            __popcll(__ballot(b2 <= mid)) + __popcll(__ballot(b3 <= mid)) +
            __popcll(__ballot(b4 <= mid)) + __popcll(__ballot(b5 <= mid));
    if (c >= 30) hi = mid; else lo = mid + 1;
  }
  unsigned tau = hi;

  float dsum = 0.0f;
  {
    unsigned mm[12] = {a0,a1,a2,a3,a4,a5,b0,b1,b2,b3,b4,b5};
#pragma unroll
    for (int r = 0; r < 12; ++r){
      if (mm[r] <= tau){
        int idx = (int)(mm[r] & 0xFFFu);
        const float* qq = shb + (size_t)idx * 6;
        dsum += fabsf(fmaf(nx, qq[3], fmaf(ny, qq[4], nz * qq[5])));
      }
    }
  }
  dsum = wave_sum(dsum);

  const float* skb = skel + (size_t)b * NS * 3;
  const float* nb  = nori + (size_t)b * NS * 3;
  unsigned u0=~0u,u1=~0u,u2=~0u; int i0=0,i1=0,i2=0;
#pragma unroll
  for (int it = 0; it < 4; ++it){
    int n2i = it * 64 + lane;
    float dx = skb[n2i*3+0] - cx, dy = skb[n2i*3+1] - cy, dz = skb[n2i*3+2] - cz;
    unsigned u = __float_as_uint(fmaf(dx,dx,fmaf(dy,dy,dz*dz)));
    if (u < u2){ u2 = u; i2 = n2i; }
    if (u2 < u1){ unsigned t=u1;u1=u2;u2=t; int ti=i1;i1=i2;i2=ti; }
    if (u1 < u0){ unsigned t=u0;u0=u1;u1=t; int ti=i0;i0=i1;i1=ti; }
  }
  int cc = 0;
  float nssum = 0.0f;
#pragma unroll
  for (int r = 0; r < 3; ++r){
    unsigned hu = (cc==0)?u0:((cc==1)?u1:u2);
    int      hix= (cc==0)?i0:((cc==1)?i1:i2);
    unsigned long long pack = (((unsigned long long)hu) << 32) | (unsigned)hix;
    unsigned long long best = wave_min_u64(pack);
    if (pack == best) cc++;
    int idx = (int)(best & 0xffffffffull);
    if (lane == 0){
      float axn = nb[idx*3+0]-nx, ayn = nb[idx*3+1]-ny, azn = nb[idx*3+2]-nz;
      nssum += sqrtf(fmaf(axn,axn,fmaf(ayn,ayn,azn*azn)) + EPS);
    }
  }

  if (lane == 0){
    float nrm = sqrtf(nx*nx + ny*ny + nz*nz + EPS);
    float ndv = expf(0.3f - nrm) + ((nrm < 0.25f) ? 5.0f : 0.0f);
    float* sko = ws + OFF_SKO + (size_t)row * 4;   // indexed write, no atomics
    sko[0] = pmin;
    sko[1] = dsum * (1.0f / 30.0f);
    sko[2] = nssum;
    sko[3] = ndv;
  }
}

// ---- dispatch 2: cd1, corner-folded: 2 skels (16 rows) per wave, quarter sweep ----
__global__ __launch_bounds__(256) void k_cd1(float* __restrict__ ws){
  const float4* skr = (const float4*)(ws + OFF_SKR);
  const float4* sxy = (const float4*)(ws + OFF_SXY);
  unsigned* c1m = (unsigned*)(ws + OFF_C1M);
  int tid  = threadIdx.x;
  int wid  = tid >> 6;
  int lane = tid & 63;
  int wv   = blockIdx.x * 4 + wid;     // 0..4095
  int pair = wv >> 2;                  // 0..1023
  int qtr  = wv & 3;
  int s0   = pair * 2;                 // global skel 0..2046 (even)
  int b    = s0 >> 8;

  float ax[2], ay[2], az[2], m2re[2], C[2][8];
#pragma unroll
  for (int s = 0; s < 2; ++s){
    float4 kr = skr[s0 + s];
    float cxx = kr.x, cyy = kr.y, czz = kr.z, rr = kr.w;
    ax[s] = -2.0f * cxx; ay[s] = -2.0f * cyy; az[s] = -2.0f * czz;
    m2re[s] = M2E * rr;
    float cw = fmaf(cxx, cxx, fmaf(cyy, cyy, czz * czz)) + rr * rr;
    float tre = 2.0f * rr * EDIR;
#pragma unroll
    for (int k = 0; k < 8; ++k){
      float sx = (k & 4) ? -cxx : cxx;
      float sy = (k & 2) ? -cyy : cyy;
      float sz = (k & 1) ? -czz : czz;
      C[s][k] = fmaf(tre, sx + sy + sz, cw);   // cw + r^2 + 2re*(dk.c)
    }
  }

  const float4* sh = sxy + (size_t)b * NP + qtr * 1024;
  float mn[2][8];
#pragma unroll
  for (int s = 0; s < 2; ++s)
#pragma unroll
    for (int k = 0; k < 8; ++k) mn[s][k] = 3.4e38f;

#pragma unroll 4
  for (int it = 0; it < 16; ++it){
    float4 p = sh[it * 64 + lane];
    float s1p = p.x + p.y, s2p = p.x - p.y;
    float ga = s1p + p.z, gb = s1p - p.z, gc = s2p + p.z, gd = s2p - p.z;
#pragma unroll
    for (int s = 0; s < 2; ++s){
      float t = fmaf(p.x, ax[s], fmaf(p.y, ay[s], fmaf(p.z, az[s], p.w)));
      float m = m2re[s];
      mn[s][0] = fminf(mn[s][0], fmaf(m,  ga, t + C[s][0]));
      mn[s][1] = fminf(mn[s][1], fmaf(m,  gb, t + C[s][1]));
      mn[s][2] = fminf(mn[s][2], fmaf(m,  gc, t + C[s][2]));
      mn[s][3] = fminf(mn[s][3], fmaf(m,  gd, t + C[s][3]));
      mn[s][4] = fminf(mn[s][4], fmaf(m, -gd, t + C[s][4]));
      mn[s][5] = fminf(mn[s][5], fmaf(m, -gc, t + C[s][5]));
      mn[s][6] = fminf(mn[s][6], fmaf(m, -gb, t + C[s][6]));
      mn[s][7] = fminf(mn[s][7], fmaf(m, -ga, t + C[s][7]));
    }
  }
#pragma unroll
  for (int s = 0; s < 2; ++s)
#pragma unroll
    for (int k = 0; k < 8; ++k){
      float m = wave_min(mn[s][k]);
      if (lane == 0) atomicMin(c1m + (size_t)(s0 + s) * 8 + k, fenc(m));
    }
}

// ---- dispatch 3: cd2/p2sn (analytic) + skn ----
__global__ __launch_bounds__(256) void k_rest2(float* __restrict__ ws){
  __shared__ float4 lsh[NM];
  __shared__ float r1[4], r2[4];
  const float4* skr = (const float4*)(ws + OFF_SKR);
  const float4* sxy = (const float4*)(ws + OFF_SXY);
  const float4* l3p = (const float4*)(ws + OFF_L3P);
  const float4* nr4 = (const float4*)(ws + OFF_NR4);
  int bid  = blockIdx.x;
  int tid  = threadIdx.x;
  int wid  = tid >> 6;
  int lane = tid & 63;

  if (bid < NBLK_CD2){
    // ---- cd2 + p2s_n: 8 shape-rows per wave; 256-skel sweep, analytic corner min ----
    int wv   = bid * 4 + wid;            // 0..4095
    int row0 = wv * 8;                   // 0..32767
    int b    = row0 >> 12;
    float cx[8], cy[8], cz[8];
#pragma unroll
    for (int i = 0; i < 8; ++i){
      float4 c = sxy[row0 + i];
      cx[i] = c.x; cy[i] = c.y; cz[i] = c.z;
    }
    const float4* kb = skr + (size_t)b * NS;
    float mn[8], pm[8];
#pragma unroll
    for (int i = 0; i < 8; ++i){ mn[i] = 3.4e38f; pm[i] = 3.4e38f; }
#pragma unroll
    for (int it = 0; it < 4; ++it){
      float4 kr = kb[it * 64 + lane];
      float rr = kr.w;
      float r2 = rr * rr;
      float c1 = M2E * rr;
#pragma unroll
      for (int i = 0; i < 8; ++i){
        float dx = cx[i] - kr.x, dy = cy[i] - kr.y, dz = cz[i] - kr.z;
        float q  = fmaf(dx, dx, fmaf(dy, dy, dz * dz));
        float s  = (fabsf(dx) + fabsf(dy)) + fabsf(dz);
        mn[i] = fminf(mn[i], fmaf(c1, s, q + r2));
        float d = sqrtf(fmaxf(q, EPS));
        pm[i] = fminf(pm[i], fabsf(d - rr));
      }
    }
    float cdv = 0.0f, pv = 0.0f;
#pragma unroll
    for (int i = 0; i < 8; ++i){
      float m = wave_min(mn[i]);
      cdv += sqrtf(fmaxf(m, EPS));
      pv  += wave_min(pm[i]);
    }
    if (lane == 0){
      float* slot = ws + (size_t)(bid & (NSLOT - 1)) * SLOTW;
      atomicAdd(slot + T_CD2, cdv);
      atomicAdd(slot + T_P2SN, pv);
    }

  } else {
    // ---- skn: thread per combine point ----
    int q  = bid - NBLK_CD2;         // 0..239
    int b  = q / 30;
    int t  = (q % 30) * 256 + tid;   // 0..7679
    lsh[tid] = l3p[(size_t)b * NM + tid];
    __syncthreads();
    int s = t >> 8;
    int j = t & 255;
    float ksf = (float)s * (1.0f / 30.0f);
    float4 sj = skr[(size_t)b * NS + j];
    float4 nj = nr4[(size_t)b * NS + j];
    float px = fmaf(nj.x, ksf, sj.x);
    float py = fmaf(nj.y, ksf, sj.y);
    float pz = fmaf(nj.z, ksf, sj.z);
    float ax = -2.0f * px, ay = -2.0f * py, az = -2.0f * pz;
    float pw = fmaf(px, px, fmaf(py, py, pz * pz));
    float mn = 3.4e38f;
#pragma unroll 8
    for (int qq = 0; qq < NM; ++qq){
      float4 L = lsh[qq];
      float t2 = fmaf(L.x, ax, fmaf(L.y, ay, fmaf(L.z, az, L.w)));
      mn = fminf(mn, t2);
    }
    float d = sqrtf(fmaxf(mn + pw, EPS));
    float s1 = wave_sum(d);
    float s2 = wave_sum(d * d);
    if (lane == 0){ r1[wid] = s1; r2[wid] = s2; }
    __syncthreads();
    if (tid == 0){
      float a1 = r1[0]+r1[1]+r1[2]+r1[3];
      float a2 = r2[0]+r2[1]+r2[2]+r2[3];
      float* slot = ws + (size_t)(bid & (NSLOT - 1)) * SLOTW;
      atomicAdd(slot + T_SKN_SUM + b, a1);
      atomicAdd(slot + T_SKN_SQ  + b, a2);
    }
  }
}

// ---- finalize ----
__global__ __launch_bounds__(256) void k_final(const float* __restrict__ rad,
                                               const float* __restrict__ ws,
                                               const int* w0, const int* w1, const int* w2,
                                               const int* w4, const int* w5, const int* w6,
                                               float* __restrict__ out){
  __shared__ float A[SLOTW];
  __shared__ float red[6][4];
  int tid = threadIdx.x;
  int wid = tid >> 6, lane = tid & 63;
  if (tid < SLOTW){
    float v = 0.0f;
    for (int s = 0; s < NSLOT; ++s) v += ws[(size_t)s * SLOTW + tid];
    A[tid] = v;
  }
  float prad = 0.0f;
  for (int q = tid; q < NB * NS; q += 256) prad += rad[q];
  // cd1: decode per-row min dist^2
  const unsigned* c1m = (const unsigned*)(ws + OFF_C1M);
  float pc1 = 0.0f;
  for (int q = tid; q < NB * 2048; q += 256){
    unsigned u = c1m[q];
    float m = (u & 0x80000000u) ? __uint_as_float(u ^ 0x80000000u) : __uint_as_float(~u);
    pc1 += sqrtf(fmaxf(m, EPS));
  }
  // skelrow per-row outputs
  const float* sko = ws + OFF_SKO;
  float pp2sj = 0.0f, pnorm = 0.0f, pns = 0.0f, pnd = 0.0f;
  for (int q = tid; q < 2048; q += 256){
    const float* s4 = sko + (size_t)q * 4;
    pp2sj += s4[0]; pnorm += s4[1]; pns += s4[2]; pnd += s4[3];
  }
  prad  = wave_sum(prad);
  pc1   = wave_sum(pc1);
  pp2sj = wave_sum(pp2sj);
  pnorm = wave_sum(pnorm);
  pns   = wave_sum(pns);
  pnd   = wave_sum(pnd);
  if (lane == 0){
    red[0][wid] = prad; red[1][wid] = pc1; red[2][wid] = pp2sj;
    red[3][wid] = pnorm; red[4][wid] = pns; red[5][wid] = pnd;
  }
  __syncthreads();
  if (tid == 0){
    float srad = red[0][0]+red[0][1]+red[0][2]+red[0][3];
    float c1t  = red[1][0]+red[1][1]+red[1][2]+red[1][3];
    float p2sj = red[2][0]+red[2][1]+red[2][2]+red[2][3];
    float nrmt = red[3][0]+red[3][1]+red[3][2]+red[3][3];
    float nst  = red[4][0]+red[4][1]+red[4][2]+red[4][3];
    float ndt  = red[5][0]+red[5][1]+red[5][2]+red[5][3];
    float ls = c1t * (1.0f/2048.0f) + A[T_CD2] * (1.0f/4096.0f);
    float lp = A[T_P2SN] * (1.0f/4096.0f) + p2sj * (1.0f/256.0f);
    float lr = -srad * (1.0f/256.0f);
    float ln = nrmt * (1.0f/8.0f);
    float smind = 0.0f, vsum = 0.0f;
    for (int bb = 0; bb < NB; ++bb){
      float s1 = A[T_SKN_SUM + bb], s2 = A[T_SKN_SQ + bb];
      smind += s1;
      vsum  += (s2 - s1 * s1 * (1.0f/7680.0f)) * (1.0f/7679.0f);
    }
    float lskn = 50.0f * smind * (1.0f/(8.0f*7680.0f)) + 500.0f * vsum * (1.0f/8.0f);
    float lnd = ndt * (1.0f/2048.0f);
    float lns = nst * (1.0f/6144.0f);
    float o = (float)w0[0]*ls + (float)w1[0]*lp + (float)w2[0]*lr +
              (float)w4[0]*ln + (float)w5[0]*lskn + (float)w6[0]*lnd + 0.1f*lns;
    out[0] = o;
  }
}

extern "C" void kernel_launch(void* const* d_in, const int* in_sizes, int n_in,
                              void* d_out, int out_size, void* d_ws, size_t ws_size,
                              hipStream_t stream) {
  const float* skel  = (const float*)d_in[0];
  const float* rad   = (const float*)d_in[1];
  const float* nori  = (const float*)d_in[3];
  const float* l3    = (const float*)d_in[5];
  const float* shape = (const float*)d_in[7];
  const int* w0 = (const int*)d_in[9];
  const int* w1 = (const int*)d_in[10];
  const int* w2 = (const int*)d_in[11];
  const int* w4 = (const int*)d_in[13];
  const int* w5 = (const int*)d_in[14];
  const int* w6 = (const int*)d_in[15];
  float* ws  = (float*)d_ws;
  float* out = (float*)d_out;

  k_sp<<<dim3(NBLK_SP), dim3(256), 0, stream>>>(skel, rad, nori, l3, shape, ws);
  k_cd1<<<dim3(NBLK_CD1), dim3(256), 0, stream>>>(ws);
  k_rest2<<<dim3(NBLK_REST2), dim3(256), 0, stream>>>(ws);
  k_final<<<dim3(1), dim3(256), 0, stream>>>(rad, ws, w0, w1, w2, w4, w5, w6, out);
}

// Round 13
// 53.972 us; speedup vs baseline: 1.6576x; 1.5893x over previous
//
#include <hip/hip_runtime.h>
#include <math.h>

#define EPS 1e-12f
#define EDIR 0.57735027f
#define M2E  -1.15470054f   // -2*EDIR

#define NB 8      // batches
#define NS 256    // skel points
#define NP 4096   // shape points
#define NM 256    // l3 points

// k_mega role block ranges
#define NBLK_SKEL 512
#define NBLK_CD1  512
#define NBLK_CD2  1024
#define NBLK_SKN  240
#define B0_CD1  (NBLK_SKEL)
#define B0_CD2  (B0_CD1 + NBLK_CD1)
#define B0_SKN  (B0_CD2 + NBLK_CD2)
#define NBLK_MEGA (B0_SKN + NBLK_SKN)

// ws layout (floats) — every slot written every call; no init needed
#define OFF_SKO 0                       // 2048 rows x 4: pmin, norm, ns, nd
#define OFF_C1O (OFF_SKO + 2048*4)      // 2048: per-skel cd1 partial (sum of 8 sqrt-mins)
#define OFF_C2O (OFF_C1O + 2048)        // 4096: per-wave cd2 partial
#define OFF_P2O (OFF_C2O + 4096)        // 4096: per-wave p2s_n partial
#define OFF_SKS (OFF_P2O + 4096)        // 240: skn block sum
#define OFF_SKQ (OFF_SKS + 240)         // 240: skn block sumsq

__device__ __forceinline__ unsigned umin2(unsigned a, unsigned b){ return a<b?a:b; }
__device__ __forceinline__ unsigned umax2(unsigned a, unsigned b){ return a>b?a:b; }

__device__ __forceinline__ float wave_min(float v){
#pragma unroll
  for (int o = 32; o; o >>= 1) v = fminf(v, __shfl_xor(v, o));
  return v;
}
__device__ __forceinline__ float wave_max(float v){
#pragma unroll
  for (int o = 32; o; o >>= 1) v = fmaxf(v, __shfl_xor(v, o));
  return v;
}
__device__ __forceinline__ float wave_sum(float v){
#pragma unroll
  for (int o = 32; o; o >>= 1) v += __shfl_xor(v, o);
  return v;
}
__device__ __forceinline__ unsigned wave_min_u(unsigned v){
#pragma unroll
  for (int o = 32; o; o >>= 1){ unsigned w = __shfl_xor(v, o); v = (w < v) ? w : v; }
  return v;
}
__device__ __forceinline__ unsigned wave_max_u(unsigned v){
#pragma unroll
  for (int o = 32; o; o >>= 1){ unsigned w = __shfl_xor(v, o); v = (w > v) ? w : v; }
  return v;
}
__device__ __forceinline__ unsigned long long wave_min_u64(unsigned long long v){
#pragma unroll
  for (int o = 32; o; o >>= 1){
    unsigned long long w = __shfl_xor(v, o);
    v = (w < v) ? w : v;
  }
  return v;
}

// ---- dispatch 1: all roles, raw inputs, indexed outputs, no atomics/fences ----
__global__ __launch_bounds__(256) void k_mega(const float* __restrict__ skel,
                                              const float* __restrict__ rad,
                                              const float* __restrict__ nori,
                                              const float* __restrict__ l3,
                                              const float* __restrict__ shape,
                                              float* __restrict__ ws){
  __shared__ float4 lsh[NM];
  __shared__ float r1[4], r2[4];
  int bid  = blockIdx.x;
  int tid  = threadIdx.x;
  int wid  = tid >> 6;
  int lane = tid & 63;

  if (bid < B0_CD1){
    // ---- skelrow: per (b, skel j): p2s_j + top30 normal + top3 ns + nd ----
    int row = bid * 4 + wid;          // 0..2047
    int b = row >> 8;
    const float* sjp = skel + (size_t)row * 3;
    float cx = sjp[0], cy = sjp[1], cz = sjp[2];
    float rj = rad[row];
    float r2j = rj * rj;
    const float* njp = nori + (size_t)row * 3;
    float nx = njp[0], ny = njp[1], nz = njp[2];
    const float* shb = shape + (size_t)b * NP * 6;

    unsigned a0=~0u,a1=~0u,a2=~0u,a3=~0u,a4=~0u,a5=~0u;
    unsigned b0=~0u,b1=~0u,b2=~0u,b3=~0u,b4=~0u,b5=~0u;
    float dmoA = 3.4e38f, dmiA = -3.4e38f, dmoB = 3.4e38f, dmiB = -3.4e38f;

#pragma unroll 2
    for (int s = 0; s < 32; ++s){
      int nA = s * 128 + lane;
      int nB = nA + 64;
      float2 xyA = *(const float2*)(shb + (size_t)nA * 6);
      float  zA  = shb[(size_t)nA * 6 + 2];
      float2 xyB = *(const float2*)(shb + (size_t)nB * 6);
      float  zB  = shb[(size_t)nB * 6 + 2];
      float dxA = xyA.x - cx, dyA = xyA.y - cy, dzA = zA - cz;
      float dxB = xyB.x - cx, dyB = xyB.y - cy, dzB = zB - cz;
      float dA = fmaf(dxA, dxA, fmaf(dyA, dyA, dzA * dzA));
      float dB = fmaf(dxB, dxB, fmaf(dyB, dyB, dzB * dzB));
      bool inA = dA < r2j;
      bool inB = dB < r2j;
      dmoA = fminf(dmoA, inA ? 3.4e38f : dA);
      dmiA = fmaxf(dmiA, inA ? dA : -3.4e38f);
      dmoB = fminf(dmoB, inB ? 3.4e38f : dB);
      dmiB = fmaxf(dmiB, inB ? dB : -3.4e38f);
      unsigned uA = (__float_as_uint(dA) & 0xFFFFF000u) | (unsigned)nA;
      unsigned uB = (__float_as_uint(dB) & 0xFFFFF000u) | (unsigned)nB;
      a5 = umin2(a5, uA);
      { unsigned p = umin2(a4, a5), q = umax2(a4, a5); a4 = p; a5 = q; }
      { unsigned p = umin2(a3, a4), q = umax2(a3, a4); a3 = p; a4 = q; }
      { unsigned p = umin2(a2, a3), q = umax2(a2, a3); a2 = p; a3 = q; }
      { unsigned p = umin2(a1, a2), q = umax2(a1, a2); a1 = p; a2 = q; }
      { unsigned p = umin2(a0, a1), q = umax2(a0, a1); a0 = p; a1 = q; }
      b5 = umin2(b5, uB);
      { unsigned p = umin2(b4, b5), q = umax2(b4, b5); b4 = p; b5 = q; }
      { unsigned p = umin2(b3, b4), q = umax2(b3, b4); b3 = p; b4 = q; }
      { unsigned p = umin2(b2, b3), q = umax2(b2, b3); b2 = p; b3 = q; }
      { unsigned p = umin2(b1, b2), q = umax2(b1, b2); b1 = p; b2 = q; }
      { unsigned p = umin2(b0, b1), q = umax2(b0, b1); b0 = p; b1 = q; }
    }
    float dmin_out = wave_min(fminf(dmoA, dmoB));
    float dmax_in  = wave_max(fmaxf(dmiA, dmiB));
    float pmin = sqrtf(fmaxf(dmin_out, EPS)) - rj;
    float pin  = (dmax_in >= 0.0f) ? (rj - sqrtf(fmaxf(dmax_in, EPS))) : 3.4e38f;
    pmin = fminf(pmin, pin);

    unsigned lmin = umin2(a0, b0);
    unsigned lo = wave_min_u(lmin), hi = wave_max_u(lmin);
    while (lo < hi){
      unsigned mid = lo + ((hi - lo) >> 1);
      int c = __popcll(__ballot(a0 <= mid)) + __popcll(__ballot(a1 <= mid)) +
              __popcll(__ballot(a2 <= mid)) + __popcll(__ballot(a3 <= mid)) +
              __popcll(__ballot(a4 <= mid)) + __popcll(__ballot(a5 <= mid)) +
              __popcll(__ballot(b0 <= mid)) + __popcll(__ballot(b1 <= mid)) +
              __popcll(__ballot(b2 <= mid)) + __popcll(__ballot(b3 <= mid)) +
              __popcll(__ballot(b4 <= mid)) + __popcll(__ballot(b5 <= mid));
      if (c >= 30) hi = mid; else lo = mid + 1;
    }
    unsigned tau = hi;

    float dsum = 0.0f;
    {
      unsigned mm[12] = {a0,a1,a2,a3,a4,a5,b0,b1,b2,b3,b4,b5};
#pragma unroll
      for (int r = 0; r < 12; ++r){
        if (mm[r] <= tau){
          int idx = (int)(mm[r] & 0xFFFu);
          const float* qq = shb + (size_t)idx * 6;
          dsum += fabsf(fmaf(nx, qq[3], fmaf(ny, qq[4], nz * qq[5])));
        }
      }
    }
    dsum = wave_sum(dsum);

    const float* skb = skel + (size_t)b * NS * 3;
    const float* nb  = nori + (size_t)b * NS * 3;
    unsigned u0=~0u,u1=~0u,u2=~0u; int i0=0,i1=0,i2=0;
#pragma unroll
    for (int it = 0; it < 4; ++it){
      int n2i = it * 64 + lane;
      float dx = skb[n2i*3+0] - cx, dy = skb[n2i*3+1] - cy, dz = skb[n2i*3+2] - cz;
      unsigned u = __float_as_uint(fmaf(dx,dx,fmaf(dy,dy,dz*dz)));
      if (u < u2){ u2 = u; i2 = n2i; }
      if (u2 < u1){ unsigned t=u1;u1=u2;u2=t; int ti=i1;i1=i2;i2=ti; }
      if (u1 < u0){ unsigned t=u0;u0=u1;u1=t; int ti=i0;i0=i1;i1=ti; }
    }
    int cc = 0;
    float nssum = 0.0f;
#pragma unroll
    for (int r = 0; r < 3; ++r){
      unsigned hu = (cc==0)?u0:((cc==1)?u1:u2);
      int      hix= (cc==0)?i0:((cc==1)?i1:i2);
      unsigned long long pack = (((unsigned long long)hu) << 32) | (unsigned)hix;
      unsigned long long best = wave_min_u64(pack);
      if (pack == best) cc++;
      int idx = (int)(best & 0xffffffffull);
      if (lane == 0){
        float axn = nb[idx*3+0]-nx, ayn = nb[idx*3+1]-ny, azn = nb[idx*3+2]-nz;
        nssum += sqrtf(fmaf(axn,axn,fmaf(ayn,ayn,azn*azn)) + EPS);
      }
    }

    if (lane == 0){
      float nrm = sqrtf(nx*nx + ny*ny + nz*nz + EPS);
      float ndv = expf(0.3f - nrm) + ((nrm < 0.25f) ? 5.0f : 0.0f);
      float* sko = ws + OFF_SKO + (size_t)row * 4;
      sko[0] = pmin;
      sko[1] = dsum * (1.0f / 30.0f);
      sko[2] = nssum;
      sko[3] = ndv;
    }

  } else if (bid < B0_CD2){
    // ---- cd1 corner-folded: 1 skel (8 corner-rows) per wave, raw shape sweep ----
    int s0 = (bid - B0_CD1) * 4 + wid;   // 0..2047
    int b  = s0 >> 8;
    const float* sp = skel + (size_t)s0 * 3;
    float cx = sp[0], cy = sp[1], cz = sp[2];
    float rr = rad[s0];
    float m2re = M2E * rr;
    const float* shb = shape + (size_t)b * NP * 6;
    float mn[8];
#pragma unroll
    for (int k = 0; k < 8; ++k) mn[k] = 3.4e38f;
#pragma unroll 4
    for (int s = 0; s < 64; ++s){
      int n = s * 64 + lane;
      float2 xy = *(const float2*)(shb + (size_t)n * 6);
      float pz  = shb[(size_t)n * 6 + 2];
      float dx = xy.x - cx, dy = xy.y - cy, dz = pz - cz;
      float q  = fmaf(dx, dx, fmaf(dy, dy, dz * dz));
      float s1p = dx + dy, s2p = dx - dy;
      float ga = s1p + dz, gb = s1p - dz, gc = s2p + dz, gd = s2p - dz;
      mn[0] = fminf(mn[0], fmaf(m2re,  ga, q));
      mn[1] = fminf(mn[1], fmaf(m2re,  gb, q));
      mn[2] = fminf(mn[2], fmaf(m2re,  gc, q));
      mn[3] = fminf(mn[3], fmaf(m2re,  gd, q));
      mn[4] = fminf(mn[4], fmaf(m2re, -gd, q));
      mn[5] = fminf(mn[5], fmaf(m2re, -gc, q));
      mn[6] = fminf(mn[6], fmaf(m2re, -gb, q));
      mn[7] = fminf(mn[7], fmaf(m2re, -ga, q));
    }
    float r2v = rr * rr;
    float v = 0.0f;
#pragma unroll
    for (int k = 0; k < 8; ++k){
      float m = wave_min(mn[k]);
      v += sqrtf(fmaxf(m + r2v, EPS));
    }
    if (lane == 0) ws[OFF_C1O + s0] = v;

  } else if (bid < B0_SKN){
    // ---- cd2 + p2s_n: 8 shape-rows per wave; raw 256-skel sweep, analytic corner min ----
    int wv   = (bid - B0_CD2) * 4 + wid;   // 0..4095
    int row0 = wv * 8;                     // 0..32767
    int b    = row0 >> 12;
    float cx[8], cy[8], cz[8];
#pragma unroll
    for (int i = 0; i < 8; ++i){
      const float* qp = shape + (size_t)(row0 + i) * 6;
      cx[i] = qp[0]; cy[i] = qp[1]; cz[i] = qp[2];
    }
    const float* skb = skel + (size_t)b * NS * 3;
    const float* rdb = rad + (size_t)b * NS;
    float mn[8], pm[8];
#pragma unroll
    for (int i = 0; i < 8; ++i){ mn[i] = 3.4e38f; pm[i] = 3.4e38f; }
#pragma unroll
    for (int it = 0; it < 4; ++it){
      int kidx = it * 64 + lane;
      float kx = skb[kidx*3+0], ky = skb[kidx*3+1], kz = skb[kidx*3+2];
      float rr = rdb[kidx];
      float r2 = rr * rr;
      float c1 = M2E * rr;
#pragma unroll
      for (int i = 0; i < 8; ++i){
        float dx = cx[i] - kx, dy = cy[i] - ky, dz = cz[i] - kz;
        float q  = fmaf(dx, dx, fmaf(dy, dy, dz * dz));
        float s  = (fabsf(dx) + fabsf(dy)) + fabsf(dz);
        mn[i] = fminf(mn[i], fmaf(c1, s, q + r2));
        float d = sqrtf(fmaxf(q, EPS));
        pm[i] = fminf(pm[i], fabsf(d - rr));
      }
    }
    float cdv = 0.0f, pv = 0.0f;
#pragma unroll
    for (int i = 0; i < 8; ++i){
      float m = wave_min(mn[i]);
      cdv += sqrtf(fmaxf(m, EPS));
      pv  += wave_min(pm[i]);
    }
    if (lane == 0){
      ws[OFF_C2O + wv] = cdv;
      ws[OFF_P2O + wv] = pv;
    }

  } else {
    // ---- skn: thread per combine point; raw inputs, l3 staged to LDS ----
    int q  = bid - B0_SKN;           // 0..239
    int b  = q / 30;
    int t  = (q % 30) * 256 + tid;   // 0..7679
    {
      const float* lp = l3 + (size_t)(b * NM + tid) * 3;
      float lx = lp[0], ly = lp[1], lz = lp[2];
      lsh[tid] = make_float4(lx, ly, lz, fmaf(lx, lx, fmaf(ly, ly, lz * lz)));
    }
    __syncthreads();
    int s = t >> 8;
    int j = t & 255;
    float ksf = (float)s * (1.0f / 30.0f);
    const float* sj = skel + (size_t)(b * NS + j) * 3;
    const float* nj = nori + (size_t)(b * NS + j) * 3;
    float px = fmaf(nj[0], ksf, sj[0]);
    float py = fmaf(nj[1], ksf, sj[1]);
    float pz = fmaf(nj[2], ksf, sj[2]);
    float ax = -2.0f * px, ay = -2.0f * py, az = -2.0f * pz;
    float pw = fmaf(px, px, fmaf(py, py, pz * pz));
    float mn = 3.4e38f;
#pragma unroll 8
    for (int qq = 0; qq < NM; ++qq){
      float4 L = lsh[qq];
      float t2 = fmaf(L.x, ax, fmaf(L.y, ay, fmaf(L.z, az, L.w)));
      mn = fminf(mn, t2);
    }
    float d = sqrtf(fmaxf(mn + pw, EPS));
    float s1 = wave_sum(d);
    float s2 = wave_sum(d * d);
    if (lane == 0){ r1[wid] = s1; r2[wid] = s2; }
    __syncthreads();
    if (tid == 0){
      ws[OFF_SKS + q] = r1[0]+r1[1]+r1[2]+r1[3];
      ws[OFF_SKQ + q] = r2[0]+r2[1]+r2[2]+r2[3];
    }
  }
}

// ---- dispatch 2: finalize (parallel loads, LDS reductions) ----
__global__ __launch_bounds__(256) void k_final(const float* __restrict__ rad,
                                               const float* __restrict__ ws,
                                               const int* w0, const int* w1, const int* w2,
                                               const int* w4, const int* w5, const int* w6,
                                               float* __restrict__ out){
  __shared__ float red[8][4];
  __shared__ float sb1[240], sb2[240];
  __shared__ float bb1[8], bb2[8];
  int tid = threadIdx.x;
  int wid = tid >> 6, lane = tid & 63;

  float pp2sj = 0.0f, pnorm = 0.0f, pns = 0.0f, pnd = 0.0f;
  for (int q = tid; q < 2048; q += 256){
    const float* s4 = ws + OFF_SKO + (size_t)q * 4;
    pp2sj += s4[0]; pnorm += s4[1]; pns += s4[2]; pnd += s4[3];
  }
  float pc1 = 0.0f;
  for (int q = tid; q < 2048; q += 256) pc1 += ws[OFF_C1O + q];
  float pc2 = 0.0f, pp2n = 0.0f;
  for (int q = tid; q < 4096; q += 256){
    pc2  += ws[OFF_C2O + q];
    pp2n += ws[OFF_P2O + q];
  }
  float prad = 0.0f;
  for (int q = tid; q < NB * NS; q += 256) prad += rad[q];

  if (tid < 240){ sb1[tid] = ws[OFF_SKS + tid]; sb2[tid] = ws[OFF_SKQ + tid]; }

  pp2sj = wave_sum(pp2sj); pnorm = wave_sum(pnorm);
  pns = wave_sum(pns);     pnd = wave_sum(pnd);
  pc1 = wave_sum(pc1);     pc2 = wave_sum(pc2);
  pp2n = wave_sum(pp2n);   prad = wave_sum(prad);
  if (lane == 0){
    red[0][wid] = pp2sj; red[1][wid] = pnorm; red[2][wid] = pns; red[3][wid] = pnd;
    red[4][wid] = pc1;   red[5][wid] = pc2;   red[6][wid] = pp2n; red[7][wid] = prad;
  }
  __syncthreads();
  if (tid < 8){
    float s1 = 0.0f, s2 = 0.0f;
    for (int i = 0; i < 30; ++i){ s1 += sb1[tid * 30 + i]; s2 += sb2[tid * 30 + i]; }
    bb1[tid] = s1; bb2[tid] = s2;
  }
  __syncthreads();
  if (tid == 0){
    float p2sj = red[0][0]+red[0][1]+red[0][2]+red[0][3];
    float nrmt = red[1][0]+red[1][1]+red[1][2]+red[1][3];
    float nst  = red[2][0]+red[2][1]+red[2][2]+red[2][3];
    float ndt  = red[3][0]+red[3][1]+red[3][2]+red[3][3];
    float c1t  = red[4][0]+red[4][1]+red[4][2]+red[4][3];
    float c2t  = red[5][0]+red[5][1]+red[5][2]+red[5][3];
    float p2nt = red[6][0]+red[6][1]+red[6][2]+red[6][3];
    float srad = red[7][0]+red[7][1]+red[7][2]+red[7][3];
    float ls = c1t * (1.0f/2048.0f) + c2t * (1.0f/4096.0f);
    float lp = p2nt * (1.0f/4096.0f) + p2sj * (1.0f/256.0f);
    float lr = -srad * (1.0f/256.0f);
    float ln = nrmt * (1.0f/8.0f);
    float smind = 0.0f, vsum = 0.0f;
    for (int b = 0; b < NB; ++b){
      float s1 = bb1[b], s2 = bb2[b];
      smind += s1;
      vsum  += (s2 - s1 * s1 * (1.0f/7680.0f)) * (1.0f/7679.0f);
    }
    float lskn = 50.0f * smind * (1.0f/(8.0f*7680.0f)) + 500.0f * vsum * (1.0f/8.0f);
    float lnd = ndt * (1.0f/2048.0f);
    float lns = nst * (1.0f/6144.0f);
    float o = (float)w0[0]*ls + (float)w1[0]*lp + (float)w2[0]*lr +
              (float)w4[0]*ln + (float)w5[0]*lskn + (float)w6[0]*lnd + 0.1f*lns;
    out[0] = o;
  }
}

extern "C" void kernel_launch(void* const* d_in, const int* in_sizes, int n_in,
                              void* d_out, int out_size, void* d_ws, size_t ws_size,
                              hipStream_t stream) {
  const float* skel  = (const float*)d_in[0];
  const float* rad   = (const float*)d_in[1];
  const float* nori  = (const float*)d_in[3];
  const float* l3    = (const float*)d_in[5];
  const float* shape = (const float*)d_in[7];
  const int* w0 = (const int*)d_in[9];
  const int* w1 = (const int*)d_in[10];
  const int* w2 = (const int*)d_in[11];
  const int* w4 = (const int*)d_in[13];
  const int* w5 = (const int*)d_in[14];
  const int* w6 = (const int*)d_in[15];
  float* ws  = (float*)d_ws;
  float* out = (float*)d_out;

  k_mega<<<dim3(NBLK_MEGA), dim3(256), 0, stream>>>(skel, rad, nori, l3, shape, ws);
  k_final<<<dim3(1), dim3(256), 0, stream>>>(rad, ws, w0, w1, w2, w4, w5, w6, out);
}